// Round 5
// baseline (316.770 us; speedup 1.0000x reference)
//
#include <hip/hip_runtime.h>
#include <math.h>

#define RDIM 256
#define CIN 64
#define COUT 64
#define MODES 16
#define NB 8

typedef short short8 __attribute__((ext_vector_type(8)));
typedef float f32x4 __attribute__((ext_vector_type(4)));

// f32 -> bf16 bits, round-to-nearest-even
__device__ __forceinline__ unsigned short f2b(float f) {
    unsigned u = __builtin_bit_cast(unsigned, f);
    unsigned r = (u + 0x7FFFu + ((u >> 16) & 1u)) >> 16;
    return (unsigned short)r;
}

// ---------------------------------------------------------------------------
// k_prep: blocks [0,336): twiddle/weight tables. blocks [336,848): WT transpose.
//  Tf2[kyc(32)][k(256)]: forward-y twiddles (k-permuted).
//  T2[r(64)][k(512)]: forward-x twiddles, 1/256 folded (k-permuted).
//  WbT[o][k]=bf16 Wres^T.  Tg[y][kk]: irfft y-twiddles.
//  A2[comp(2)][x(256)][k(64)]: inverse-x twiddles.
//  WT[m*16+ky][i][o] float2: mode-mix weights (for k_spec's VALU mix).
__global__ __launch_bounds__(256) void k_prep(const float* __restrict__ Wres,
                                              const float* __restrict__ fw0,
                                              const float* __restrict__ fw1,
                                              unsigned short* __restrict__ Tf2,
                                              unsigned short* __restrict__ T2,
                                              unsigned short* __restrict__ WbT,
                                              unsigned short* __restrict__ Tg,
                                              unsigned short* __restrict__ A2,
                                              float2* __restrict__ WT) {
    __shared__ float2 Ls[16][257];
    int bi = blockIdx.x;
    int t = (int)threadIdx.x;
    if (bi < 336) {
        int e = bi * 256 + t;  // [0, 86016)
        if (e < 8192) {
            int kyc = e >> 8, k = e & 255;
            int S = k >> 3, j = k & 7;
            int w = S >> 3, h = (S >> 2) & 1, q = S & 3;
            int y = w * 64 + q + 4 * (h * 8 + j);
            int ky = kyc >> 1;
            int p = (ky * y) & 255;
            float ang = (float)p * (float)(2.0 * M_PI / 256.0);
            float sz, cz;
            sincosf(ang, &sz, &cz);
            Tf2[e] = f2b((kyc & 1) ? -sz : cz);
        } else if (e < 40960) {
            int f = e - 8192;  // [0, 32768)
            int r = f >> 9, k = f & 511;
            int S = k >> 3, j = k & 7;
            int w = S >> 4, bp = (S >> 3) & 1, a = S & 7;
            int d = j >> 1, c = j & 1;
            int x = w * 64 + bp + 8 * a + 2 * d;
            int m = r >> 1, cc = r & 1;
            int kx = (m < 16) ? m : (m + 224);
            int p = (kx * x) & 255;
            float ang = (float)p * (float)(2.0 * M_PI / 256.0);
            float sz, cz;
            sincosf(ang, &sz, &cz);
            float val = (cc == 0) ? (c ? sz : cz) : (c ? cz : -sz);
            T2[f] = f2b(val * (1.0f / 256.0f));
        } else if (e < 45056) {
            int f = e - 40960;  // [0, 4096)
            int o = f >> 6, k = f & 63;
            WbT[o * 64 + k] = f2b(Wres[k * 64 + o]);
        } else if (e < 53248) {
            int f = e - 45056;  // [0, 8192)
            int y = f >> 5, kk = f & 31, ky = kk >> 1;
            int p = (ky * y) & 255;
            float ang = (float)p * (float)(2.0 * M_PI / 256.0);
            float sz, cz;
            sincosf(ang, &sz, &cz);
            Tg[f] = f2b((kk & 1) ? -sz : cz);
        } else {
            int f = e - 53248;  // [0, 32768)
            int comp = f >> 14, g = f & 16383;
            int x = g >> 6, k = g & 63;
            int m = k >> 1, c = k & 1;
            int kx = (m < 16) ? m : (m + 224);
            int p = (kx * x) & 255;
            float ang = (float)p * (float)(2.0 * M_PI / 256.0);
            float sz, cz;
            sincosf(ang, &sz, &cz);
            float val = (comp == 0) ? (c ? -sz : cz) : (c ? cz : sz);
            A2[f] = f2b(val);
        }
    } else {
        // WT transpose: fw [i,o,mx,ky,2] -> WT[m*16+ky][i][o] float2
        int blk = bi - 336;         // 0..511
        int arr = blk >> 8;
        int tile = blk & 255;
        const float2* s2 = (const float2*)(arr ? fw1 : fw0);
        for (int e = t; e < 4096; e += 256) {
            int oo = e >> 8;
            int q = e & 255;
            Ls[oo][q] = s2[(size_t)(tile * 16 + oo) * 256 + q];
        }
        __syncthreads();
        int i = (tile * 16) >> 6;
        int o0 = (tile * 16) & 63;
        for (int e = t; e < 4096; e += 256) {
            int oo = e & 15;
            int q = e >> 4;
            int mx = q >> 4, ky = q & 15;
            int m = arr * 16 + mx;
            WT[((size_t)(m * 16 + ky) * 64 + i) * 64 + o0 + oo] = Ls[oo][q];
        }
    }
}

// ---------------------------------------------------------------------------
// k_fwd_y (MFMA): A[b][ky][x][i] = sum_y X e^{-2pi i ky y/256}; also emits
// Xbf[b,x][y][i] bf16 (row-major) for k_out's direct short8 A-frag loads.
__global__ __launch_bounds__(256) void k_fwd_y(const float* __restrict__ X,
                                               const unsigned short* __restrict__ Tf,
                                               float2* __restrict__ A,
                                               unsigned short* __restrict__ Xbf) {
    __shared__ short8 Xb[64 * 32];  // 32 KB
    int b = blockIdx.x >> 8;
    int x = blockIdx.x & 255;
    int t = (int)threadIdx.x;
    int w = t >> 6;
    int l = t & 63;
    int q = l >> 4;
    int f4 = l & 15;
    int i0 = f4 * 4;

    const float4* X4 = (const float4*)(X + ((size_t)(b * 256 + x)) * 256 * 64);
    unsigned short* Xrow = Xbf + ((size_t)(b * 256 + x)) * 16384;
#pragma unroll
    for (int h = 0; h < 2; h++) {
        float4 v[8];
#pragma unroll
        for (int n = 0; n < 8; n++) {
            int y = w * 64 + q + 4 * (h * 8 + n);
            v[n] = X4[y * 16 + f4];
        }
#pragma unroll
        for (int n = 0; n < 8; n++) {
            int y = w * 64 + q + 4 * (h * 8 + n);
            *(ushort4*)(Xrow + (size_t)y * 64 + i0) =
                make_ushort4(f2b(v[n].x), f2b(v[n].y), f2b(v[n].z), f2b(v[n].w));
        }
        const float* vf = (const float*)v;
        int s = w * 8 + h * 4 + q;
#pragma unroll
        for (int di = 0; di < 4; di++) {
            int i = i0 + di;
            short8 hb;
#pragma unroll
            for (int j = 0; j < 8; j++) hb[j] = (short)f2b(vf[j * 4 + di]);
            Xb[i * 32 + (s ^ (i & 7))] = hb;
        }
    }
    __syncthreads();

    int m16 = l & 15;
    int quad = l >> 4;
    int iRow = w * 16 + m16;
    int isw = iRow & 7;

    f32x4 acc0 = (f32x4){0.f, 0.f, 0.f, 0.f};
    f32x4 acc1 = (f32x4){0.f, 0.f, 0.f, 0.f};
    const unsigned short* T0 = Tf + (size_t)m16 * 256 + quad * 8;
#pragma unroll
    for (int ks = 0; ks < 8; ks++) {
        short8 a0 = *(const short8*)(T0 + ks * 32);
        short8 a1 = *(const short8*)(T0 + 4096 + ks * 32);
        short8 bfrag = Xb[iRow * 32 + ((ks * 4 + quad) ^ isw)];
        acc0 = __builtin_amdgcn_mfma_f32_16x16x32_bf16(a0, bfrag, acc0, 0, 0, 0);
        acc1 = __builtin_amdgcn_mfma_f32_16x16x32_bf16(a1, bfrag, acc1, 0, 0, 0);
    }

    float2* Ab = A + ((size_t)(b * 16) * 256 + x) * 64;
    int ky0 = quad * 2;
    Ab[(size_t)(ky0)     * 16384 + iRow] = make_float2(acc0[0], acc0[1]);
    Ab[(size_t)(ky0 + 1) * 16384 + iRow] = make_float2(acc0[2], acc0[3]);
    Ab[(size_t)(ky0 + 8) * 16384 + iRow] = make_float2(acc1[0], acc1[1]);
    Ab[(size_t)(ky0 + 9) * 16384 + iRow] = make_float2(acc1[2], acc1[3]);
}

// ---------------------------------------------------------------------------
// k_spec: fused fwd_x + mode-mix + inv_x per (b,ky). 512 threads, 64 KB LDS.
//  Phase A: stage A-slab [256x][64i] -> Bs bf16 (k=2x+c permuted, swizzled)
//  Phase B: C(64mc x 64i) = T2 @ Bs  (MFMA, f32 out) -> Cf LDS
//  Phase C: D[m][o] = sum_i C[m][i]*w_m[i][o]  (VALU f32, per-mode weights)
//           -> bf16 B-frags Bd straight from registers
//  Phase D: G(256x x 64o, re/im) = A2 @ Bd  (MFMA) -> G global
__global__ __launch_bounds__(512) void k_spec(const float2* __restrict__ A,
                                              const unsigned short* __restrict__ T2,
                                              const float2* __restrict__ WT,
                                              const unsigned short* __restrict__ A2,
                                              float2* __restrict__ G) {
    __shared__ char Lsm[65536];
    short8* Bs = (short8*)Lsm;              // [64 iL][64 slots]
    float2* Cf = (float2*)Lsm;              // [32 m][64 i] (re,im) 16 KB
    short8* Bd = (short8*)(Lsm + 16384);    // [64 o][8 slots] 8 KB

    int bi = blockIdx.x;  // 128
    int b = bi >> 4;
    int ky = bi & 15;
    int t = (int)threadIdx.x;
    int w = t >> 6;       // 0..7
    int l = t & 63;

    // ---- phase A: stage ----
    {
        int wx = w & 3, ih = w >> 2;
        int ip = l & 15, bp = (l >> 4) & 1, ab = l >> 5;
        const float4* A4 = (const float4*)(A + ((size_t)(b * 16 + ky)) * 16384);
#pragma unroll
        for (int aa = 0; aa < 4; aa++) {
            int a = ab * 4 + aa;
            float4 v[4];
#pragma unroll
            for (int d4 = 0; d4 < 4; d4++) {
                int xx = wx * 64 + bp + 8 * a + 2 * d4;
                v[d4] = A4[xx * 32 + ih * 16 + ip];
            }
            int S = wx * 16 + bp * 8 + a;
            short8 h0, h1;
            h0[0] = (short)f2b(v[0].x); h0[1] = (short)f2b(v[0].y);
            h0[2] = (short)f2b(v[1].x); h0[3] = (short)f2b(v[1].y);
            h0[4] = (short)f2b(v[2].x); h0[5] = (short)f2b(v[2].y);
            h0[6] = (short)f2b(v[3].x); h0[7] = (short)f2b(v[3].y);
            h1[0] = (short)f2b(v[0].z); h1[1] = (short)f2b(v[0].w);
            h1[2] = (short)f2b(v[1].z); h1[3] = (short)f2b(v[1].w);
            h1[4] = (short)f2b(v[2].z); h1[5] = (short)f2b(v[2].w);
            h1[6] = (short)f2b(v[3].z); h1[7] = (short)f2b(v[3].w);
            int iL0 = (ih * 16 + ip) * 2, iL1 = iL0 + 1;
            Bs[iL0 * 64 + (S ^ (iL0 & 7))] = h0;
            Bs[iL1 * 64 + (S ^ (iL1 & 7))] = h1;
        }
    }
    __syncthreads();

    // ---- phase B: fwd_x MFMA ----
    int m16 = l & 15, quad = l >> 4;
    int ws_ = w & 3, nh = w >> 2;
    f32x4 acc[2];
    acc[0] = (f32x4){0.f, 0.f, 0.f, 0.f};
    acc[1] = (f32x4){0.f, 0.f, 0.f, 0.f};
    {
        const unsigned short* Tp = T2 + (size_t)(ws_ * 16 + m16) * 512 + quad * 8;
#pragma unroll
        for (int ks = 0; ks < 16; ks++) {
            short8 af = *(const short8*)(Tp + ks * 32);
#pragma unroll
            for (int n2 = 0; n2 < 2; n2++) {
                int iL = (nh * 2 + n2) * 16 + m16;
                short8 bfr = Bs[iL * 64 + ((ks * 4 + quad) ^ (iL & 7))];
                acc[n2] = __builtin_amdgcn_mfma_f32_16x16x32_bf16(af, bfr, acc[n2], 0, 0, 0);
            }
        }
    }
    __syncthreads();  // all waves done reading Bs

    // ---- write C into LDS (aliases Bs) ----
    {
        int m0 = ws_ * 8 + quad * 2;
#pragma unroll
        for (int n2 = 0; n2 < 2; n2++) {
            int i = (nh * 2 + n2) * 16 + m16;
            Cf[(size_t)m0 * 64 + i]       = make_float2(acc[0 + n2][0], acc[n2][1]);
            Cf[(size_t)(m0 + 1) * 64 + i] = make_float2(acc[n2][2], acc[n2][3]);
        }
    }
    __syncthreads();

    // ---- phase C: VALU mode-mix (f32), D straight to bf16 B-frags ----
    {
        int o = t & 63, mg = t >> 6;
        float dr[4], di[4];
#pragma unroll
        for (int s = 0; s < 4; s++) {
            int m = mg * 4 + s;
            const float2* Wp = WT + (size_t)(m * 16 + ky) * 4096 + o;
            const float2* Cp = Cf + (size_t)m * 64;
            float drv = 0.f, div = 0.f;
#pragma unroll 16
            for (int i = 0; i < 64; i++) {
                float2 wv = Wp[(size_t)i * 64];
                float2 cv = Cp[i];
                drv += cv.x * wv.x - cv.y * wv.y;
                div += cv.x * wv.y + cv.y * wv.x;
            }
            dr[s] = drv; di[s] = div;
        }
        short8 h;
        h[0] = (short)f2b(dr[0]); h[1] = (short)f2b(di[0]);
        h[2] = (short)f2b(dr[1]); h[3] = (short)f2b(di[1]);
        h[4] = (short)f2b(dr[2]); h[5] = (short)f2b(di[2]);
        h[6] = (short)f2b(dr[3]); h[7] = (short)f2b(di[3]);
        Bd[o * 8 + (mg ^ (o & 7))] = h;
    }
    __syncthreads();

    // ---- phase D: inv_x MFMA ----
    {
        int x0 = w * 32;
        f32x4 acc2[2][4][2];
#pragma unroll
        for (int mt = 0; mt < 2; mt++)
#pragma unroll
            for (int nt = 0; nt < 4; nt++)
#pragma unroll
                for (int c = 0; c < 2; c++) acc2[mt][nt][c] = (f32x4){0.f, 0.f, 0.f, 0.f};

#pragma unroll
        for (int ks = 0; ks < 2; ks++) {
            short8 ar[2], ai[2];
#pragma unroll
            for (int mt = 0; mt < 2; mt++) {
                int xr = x0 + mt * 16 + m16;
                ar[mt] = *(const short8*)(A2 + (size_t)xr * 64 + ks * 32 + quad * 8);
                ai[mt] = *(const short8*)(A2 + 16384 + (size_t)xr * 64 + ks * 32 + quad * 8);
            }
#pragma unroll
            for (int nt = 0; nt < 4; nt++) {
                int o2 = nt * 16 + m16;
                short8 bf = Bd[o2 * 8 + ((ks * 4 + quad) ^ (o2 & 7))];
#pragma unroll
                for (int mt = 0; mt < 2; mt++) {
                    acc2[mt][nt][0] = __builtin_amdgcn_mfma_f32_16x16x32_bf16(ar[mt], bf, acc2[mt][nt][0], 0, 0, 0);
                    acc2[mt][nt][1] = __builtin_amdgcn_mfma_f32_16x16x32_bf16(ai[mt], bf, acc2[mt][nt][1], 0, 0, 0);
                }
            }
        }

#pragma unroll
        for (int mt = 0; mt < 2; mt++)
#pragma unroll
            for (int nt = 0; nt < 4; nt++) {
                int o2 = nt * 16 + m16;
#pragma unroll
                for (int r = 0; r < 4; r++) {
                    int x = x0 + mt * 16 + quad * 4 + r;
                    G[((size_t)(b * 256 + x) * 16 + ky) * 64 + o2] =
                        make_float2(acc2[mt][nt][0][r], acc2[mt][nt][1][r]);
                }
            }
    }
}

// ---------------------------------------------------------------------------
// k_out: MFMA GEMM, K=96: out[y][o] = silu(Xbf[y][:]Wres + T[y][:]Gfold + b)
__global__ __launch_bounds__(256) void k_out(const unsigned short* __restrict__ Xbf,
                                             const float2* __restrict__ G,
                                             const unsigned short* __restrict__ WbT,
                                             const unsigned short* __restrict__ Tg,
                                             const float* __restrict__ bres,
                                             float* __restrict__ out) {
    __shared__ unsigned short Bsp[64 * 32];  // Gfold^T: [o][kk]
    int b = blockIdx.x >> 8;
    int x = blockIdx.x & 255;
    int t = (int)threadIdx.x;

    const float2* Gp = G + ((size_t)(b * 256 + x)) * 16 * 64;
    for (int e = t; e < 1024; e += 256) {
        int ky = e >> 6, o = e & 63;
        float2 g = Gp[e];
        float sc = (ky == 0) ? (1.0f / 256.0f) : (2.0f / 256.0f);
        Bsp[o * 32 + 2 * ky]     = f2b(g.x * sc);
        Bsp[o * 32 + 2 * ky + 1] = f2b(g.y * sc);
    }
    __syncthreads();

    int w = t >> 6;
    int l = t & 63;
    int m16 = l & 15;
    int quad = l >> 4;

    short8 bw0[4], bw1[4], bs[4];
    float br[4];
#pragma unroll
    for (int nt = 0; nt < 4; nt++) {
        int o = nt * 16 + m16;
        bw0[nt] = *(const short8*)(WbT + o * 64 + quad * 8);
        bw1[nt] = *(const short8*)(WbT + o * 64 + 32 + quad * 8);
        bs[nt]  = *(const short8*)(Bsp + o * 32 + quad * 8);
        br[nt]  = bres[o];
    }

    const unsigned short* Xrow = Xbf + ((size_t)(b * 256 + x)) * 16384;
    float* orow = out + ((size_t)(b * 256 + x)) * 256 * 64;

    f32x4 acc[4][4];
#pragma unroll
    for (int mt = 0; mt < 4; mt++)
#pragma unroll
        for (int nt = 0; nt < 4; nt++) acc[mt][nt] = (f32x4){0.f, 0.f, 0.f, 0.f};

#pragma unroll
    for (int mt = 0; mt < 4; mt++) {
        int y = w * 64 + mt * 16 + m16;
        short8 a0 = *(const short8*)(Xrow + (size_t)y * 64 + quad * 8);
        short8 a1 = *(const short8*)(Xrow + (size_t)y * 64 + 32 + quad * 8);
        short8 aT = *(const short8*)(Tg + (size_t)y * 32 + quad * 8);
#pragma unroll
        for (int nt = 0; nt < 4; nt++) {
            acc[mt][nt] = __builtin_amdgcn_mfma_f32_16x16x32_bf16(a0, bw0[nt], acc[mt][nt], 0, 0, 0);
            acc[mt][nt] = __builtin_amdgcn_mfma_f32_16x16x32_bf16(a1, bw1[nt], acc[mt][nt], 0, 0, 0);
            acc[mt][nt] = __builtin_amdgcn_mfma_f32_16x16x32_bf16(aT, bs[nt],  acc[mt][nt], 0, 0, 0);
        }
    }

#pragma unroll
    for (int mt = 0; mt < 4; mt++) {
#pragma unroll
        for (int nt = 0; nt < 4; nt++) {
            int o = nt * 16 + m16;
#pragma unroll
            for (int r = 0; r < 4; r++) {
                int y = w * 64 + mt * 16 + quad * 4 + r;
                float v = acc[mt][nt][r] + br[nt];
                float sg = __builtin_amdgcn_rcpf(1.0f + __expf(-v));
                orow[(size_t)y * 64 + o] = v * sg;
            }
        }
    }
}

extern "C" void kernel_launch(void* const* d_in, const int* in_sizes, int n_in,
                              void* d_out, int out_size, void* d_ws, size_t ws_size,
                              hipStream_t stream) {
    const float* X    = (const float*)d_in[0];
    const float* Wres = (const float*)d_in[1];
    const float* bres = (const float*)d_in[2];
    const float* fw0  = (const float*)d_in[3];
    const float* fw1  = (const float*)d_in[4];
    float* out = (float*)d_out;

    // workspace: A 16MB | G 16MB | WT 16MB | Xbf 64MB | tables ~170KB
    float2* A  = (float2*)d_ws;
    float2* G  = A + 2097152;
    float2* WT = G + 2097152;
    unsigned short* Xbf = (unsigned short*)(WT + 2097152);
    unsigned short* Tf2 = Xbf + 33554432;
    unsigned short* T2  = Tf2 + 8192;
    unsigned short* WbT = T2 + 32768;
    unsigned short* Tg  = WbT + 4096;
    unsigned short* A2  = Tg + 8192;

    k_prep<<<848, 256, 0, stream>>>(Wres, fw0, fw1, Tf2, T2, WbT, Tg, A2, WT);
    k_fwd_y<<<NB * 256, 256, 0, stream>>>(X, Tf2, A, Xbf);
    k_spec<<<NB * 16, 512, 0, stream>>>(A, T2, WT, A2, G);
    k_out<<<NB * 256, 256, 0, stream>>>(Xbf, G, WbT, Tg, bres, out);
}